// Round 8
// baseline (342.014 us; speedup 1.0000x reference)
//
#include <hip/hip_runtime.h>

// MPS classifier, MI355X gfx950. Round 8: r7 split-chain retiled to M=32
// -> 512 WGs -> 2 WGs/CU (the r6/r7 flat results showed 1 wave/SIMD
// serialization, not bandwidth, was the wall).
// B=8192, N=256, D=128, K=2D=256, OUT=10. fp32 in, fp32 out, fp16 MFMA.
// WG g: pair=g>>1 (rows 32*pair..+32), isR=g&1. Left: sites 1..127.
// Right: sites 254..128 (transposed weights). scalar = L_127 . R_128.
// 4 waves/WG, wave w owns cols 32w..32w+32. One barrier/step, dbuf A-frags,
// B reg-prefetch ping-pong, DPP transpose epilogue, packed-f16 phi table.

typedef _Float16 v8h __attribute__((ext_vector_type(8)));
typedef _Float16 h2  __attribute__((ext_vector_type(2)));
typedef float    v4f __attribute__((ext_vector_type(4)));

#define PI_HALF 1.5707963267948966f
#define SITE_U4 4096                       // uint4 per frag slot (64 KB)
#define RT_F32_BASE (254u*65536u/4u)       // float offset of R^T region
#define FLAG_BASE   (RT_F32_BASE + 256u*4096u)
#define MAGIC 0x13572468u

union U4H8 { uint4 u; v8h h; };

__device__ __forceinline__ v4f mfma16h(uint4 a, uint4 b, v4f c){
  U4H8 ua, ub; ua.u = a; ub.u = b;
  return __builtin_amdgcn_mfma_f32_16x16x32_f16(ua.h, ub.h, c, 0, 0, 0);
}
__device__ __forceinline__ unsigned pack2h(float lo, float hi){
  h2 p; p[0] = (_Float16)lo; p[1] = (_Float16)hi;
  return __builtin_bit_cast(unsigned, p);
}
__device__ __forceinline__ unsigned mul_phi(float v, unsigned phiu){
  _Float16 vh = (_Float16)v;
  h2 vv; vv[0] = vh; vv[1] = vh;
  h2 ph = __builtin_bit_cast(h2, phiu);
  h2 r = vv * ph;
  return __builtin_bit_cast(unsigned, r);
}
__device__ __forceinline__ unsigned dpp_xor1(unsigned x){
  return (unsigned)__builtin_amdgcn_mov_dpp((int)x, 0xB1, 0xF, 0xF, true);
}
__device__ __forceinline__ unsigned dpp_xor2(unsigned x){
  return (unsigned)__builtin_amdgcn_mov_dpp((int)x, 0x4E, 0xF, 0xF, true);
}
__device__ __forceinline__ void xpose4(const unsigned u[4], unsigned f[4], int t){
  unsigned q0 = dpp_xor1(u[0]), q1 = dpp_xor1(u[1]);
  unsigned q2 = dpp_xor1(u[2]), q3 = dpp_xor1(u[3]);
  bool b0 = (t & 1);
  unsigned h0 = b0 ? q1 : u[0];
  unsigned h1 = b0 ? u[1] : q0;
  unsigned h2_ = b0 ? q3 : u[2];
  unsigned h3 = b0 ? u[3] : q2;
  unsigned r0 = dpp_xor2(h0), r1 = dpp_xor2(h1);
  unsigned r2 = dpp_xor2(h2_), r3 = dpp_xor2(h3);
  bool b1 = (t & 2);
  f[0] = b1 ? r2 : h0;
  f[1] = b1 ? r3 : h1;
  f[2] = b1 ? h2_ : r0;
  f[3] = b1 ? h3 : r1;
}

// ---------------------------------------------------------------------------
// Combined repack (mid read once; each site has exactly one format):
// blocks 0..507: L-format, slots 0..126 (sites 1..127):
//   wsB[slot][kt][ntg][lane] uint4, elem (lane,j) = M[k=32kt+8q+j][n], k=2l+d.
// blocks 508..2539: R-format, slots 127..253 (sites 128..254):
//   B~[k=2r+d][n=l] = midrow(l)[(k&1)*128 + (k>>1)].
// ---------------------------------------------------------------------------
__global__ __launch_bounds__(256) void repack_all(const float* __restrict__ mid,
                                                  unsigned short* __restrict__ wsB){
  const int bid = blockIdx.x;
  if (bid < 508){
    int idx  = bid * 256 + threadIdx.x;        // 127*1024
    int lg   = idx & 15;
    int nt   = (idx >> 4) & 7;
    int kt   = (idx >> 7) & 7;
    int site = idx >> 10;                      // 0..126
    int q    = lg >> 2;
    int n0   = 16*nt + 4*(lg & 3);
    const float* src = mid + (size_t)site*32768 + (size_t)(32*kt + 8*q)*128 + n0;
    float Lv[4][4], Hv[4][4];
    #pragma unroll
    for (int jp = 0; jp < 4; ++jp){
      float4 a = *(const float4*)(src + (size_t)(2*jp)*128);
      float4 b = *(const float4*)(src + (size_t)(2*jp+1)*128);
      Lv[jp][0]=a.x; Lv[jp][1]=a.y; Lv[jp][2]=a.z; Lv[jp][3]=a.w;
      Hv[jp][0]=b.x; Hv[jp][1]=b.y; Hv[jp][2]=b.z; Hv[jp][3]=b.w;
    }
    uint4* dst = (uint4*)wsB + (((size_t)(site*8 + kt)*8 + nt)*64 + 16*q + 4*(lg&3));
    #pragma unroll
    for (int t = 0; t < 4; ++t){
      uint4 o;
      o.x = pack2h(Lv[0][t], Hv[0][t]);
      o.y = pack2h(Lv[1][t], Hv[1][t]);
      o.z = pack2h(Lv[2][t], Hv[2][t]);
      o.w = pack2h(Lv[3][t], Hv[3][t]);
      dst[t] = o;
    }
  } else {
    int idx  = (bid - 508) * 256 + threadIdx.x;  // 127*4096
    int lane = idx & 63;
    int ntg  = (idx >> 6) & 7;
    int kt   = (idx >> 9) & 7;
    int site = 127 + (idx >> 12);                // 127..253
    int q    = lane >> 4;
    int n    = 16*ntg + (lane & 15);
    int rb   = 16*kt + 4*q;
    const float* row = mid + (size_t)site*32768 + (size_t)n*256;
    float4 d0 = *(const float4*)(row + rb);
    float4 d1 = *(const float4*)(row + 128 + rb);
    unsigned p0 = pack2h(d0.x, d1.x);
    unsigned p1 = pack2h(d0.y, d1.y);
    unsigned p2 = pack2h(d0.z, d1.z);
    unsigned p3 = pack2h(d0.w, d1.w);
    ((uint4*)wsB)[((size_t)(site*8 + kt)*8 + ntg)*64 + lane] =
        make_uint4(p0, p1, p2, p3);
  }
}

// ---------------------------------------------------------------------------
// Main. 512 WGs x 256 thr (2 WGs/CU). LDS: phiT[128 sites][32 rows] packed
// f16 (cos,sin) = 16 KB; AfragU[2 buf][2 mt][8 kt][64 lane][4 jp] = 2*16 KB;
// scal[32]. Total ~48.3 KB -> two WGs fit per CU.
// A-frag: lane L holds A[m=16mt+(L&15)][k=32kt+8(L>>4)+j].
// ---------------------------------------------------------------------------
__global__ __launch_bounds__(256, 2) void mps_main(
    const float* __restrict__ x,               // [8192][256]
    const float* __restrict__ first,           // [2][128]
    const unsigned short* __restrict__ wsB,    // frag slots 0..253
    const float* __restrict__ lastw,           // [128][2]
    const float* __restrict__ wlin,            // [10]
    const float* __restrict__ blin,            // [10]
    float* __restrict__ ws_f,                  // ws as float (R^T + flags)
    float* __restrict__ out)                   // [8192][10]
{
  __shared__ unsigned phiT[128*32];
  __shared__ unsigned AfragU[2*2*8*64*4];      // 2 bufs x 4096 uints
  __shared__ float scal[32];

  const int tid  = threadIdx.x;
  const int g    = blockIdx.x;
  const int pair = g >> 1;
  const int isR  = g & 1;
  const int w    = tid >> 6;                   // wave: cols [32w, 32w+32)
  const int lane = tid & 63;
  const int r    = lane & 15;
  const int q    = lane >> 4;
  const int rowbase = pair * 32;
  const int phbase  = isR ? 128 : 0;

  float* RT = ws_f + RT_F32_BASE + (size_t)pair * 4096;  // [col][row] f32
  unsigned* flagp = (unsigned*)(ws_f + FLAG_BASE) + pair;

  // ---- Phase 1: feature map -> packed f16 (cos,sin), own half only ----
  {
    const int row = tid >> 3;            // 0..31
    const int c   = tid & 7;             // 32-site chunk
    const float4* xp = (const float4*)(x + (size_t)(rowbase + row) * 256 + c*32);
    float xv[32];
    float vmin = 3.0e38f, vmax = -3.0e38f;
    #pragma unroll
    for (int cc = 0; cc < 8; ++cc){
      float4 u = xp[cc];
      xv[cc*4+0]=u.x; xv[cc*4+1]=u.y; xv[cc*4+2]=u.z; xv[cc*4+3]=u.w;
      vmin = fminf(vmin, fminf(fminf(u.x,u.y), fminf(u.z,u.w)));
      vmax = fmaxf(vmax, fmaxf(fmaxf(u.x,u.y), fmaxf(u.z,u.w)));
    }
    #pragma unroll
    for (int m = 1; m < 8; m <<= 1){
      vmin = fminf(vmin, __shfl_xor(vmin, m));
      vmax = fmaxf(vmax, __shfl_xor(vmax, m));
    }
    const float sc = PI_HALF / (vmax - vmin + 1e-6f);
    #pragma unroll
    for (int j = 0; j < 32; ++j){
      int site = c*32 + j;
      int loc  = site - phbase;
      if (loc >= 0 && loc < 128){
        float a = (xv[j] - vmin) * sc;
        phiT[loc*32 + row] = pack2h(__cosf(a), __sinf(a));
      }
    }
  }
  __syncthreads();

  // ---- Phase 2: seed A-frags for step 0 (buf 0) ----
  // left : A_1[b][2l+d] = (first[l]c0+first[128+l]s0)*phi(1)[b,d]
  // right: A~254[b][2r+d] = (lastw[2r]c255+lastw[2r+1]s255)*phi(254)[b,d]
  {
    const int s_init = isR ? 127 : 0;
    const int s_next = isR ? 126 : 1;
    #pragma unroll
    for (int mt = 0; mt < 2; ++mt){
      const int m = 16*mt + r;
      h2 ph0 = __builtin_bit_cast(h2, phiT[s_init*32 + m]);
      const float c0v = (float)ph0[0], s0v = (float)ph0[1];
      const unsigned phn = phiT[s_next*32 + m];
      #pragma unroll
      for (int ktb = 0; ktb < 2; ++ktb){
        const int kt = 2*w + ktb;
        unsigned u[4];
        #pragma unroll
        for (int jp = 0; jp < 4; ++jp){
          const int l = 16*kt + 4*q + jp;
          float f0 = isR ? lastw[2*l]     : first[l];
          float f1 = isR ? lastw[2*l + 1] : first[128 + l];
          float v  = f0*c0v + f1*s0v;
          u[jp] = mul_phi(v, phn);
        }
        *(uint4*)&AfragU[((mt*8 + kt)*64 + lane)*4] =
            make_uint4(u[0], u[1], u[2], u[3]);
      }
    }
  }

  // ---- B prefetch step 0 (slot: left = t, right = 253-t) ----
  uint4 Breg0[16], Breg1[16];
  {
    const int slot = isR ? 253 : 0;
    const uint4* bp = (const uint4*)wsB + (size_t)slot * SITE_U4;
    #pragma unroll
    for (int kt = 0; kt < 8; ++kt)
      #pragma unroll
      for (int nb = 0; nb < 2; ++nb)
        Breg0[kt*2+nb] = bp[(size_t)(kt*8 + 2*w + nb)*64 + lane];
  }

  const int t3   = lane & 3;
  const int lamf = 16*((lane>>2)&3) + 4*(lane>>4) + t3;

  auto body = [&](int t, uint4 (&Bcur)[16], uint4 (&Bnxt)[16]){
    __syncthreads();

    // prefetch B for step t+1 (clamped; unused at t=126)
    {
      const int tn   = (t < 126) ? (t + 1) : 126;
      const int slot = isR ? (253 - tn) : tn;
      const uint4* bp = (const uint4*)wsB + (size_t)slot * SITE_U4;
      #pragma unroll
      for (int kt = 0; kt < 8; ++kt)
        #pragma unroll
        for (int nb = 0; nb < 2; ++nb)
          Bnxt[kt*2+nb] = bp[(size_t)(kt*8 + 2*w + nb)*64 + lane];
    }

    // MFMA: C[0..32)[32w..32w+32)
    v4f acc[2][2] = {};   // [mt][nb]; row=16mt+4q+reg, col=16(2w+nb)+r
    const unsigned* Abuf = &AfragU[(t & 1) * 4096];
    #pragma unroll
    for (int kt = 0; kt < 8; ++kt){
      uint4 a0 = *(const uint4*)&Abuf[((0*8 + kt)*64 + lane)*4];
      uint4 a1 = *(const uint4*)&Abuf[((1*8 + kt)*64 + lane)*4];
      acc[0][0] = mfma16h(a0, Bcur[kt*2+0], acc[0][0]);
      acc[0][1] = mfma16h(a0, Bcur[kt*2+1], acc[0][1]);
      acc[1][0] = mfma16h(a1, Bcur[kt*2+0], acc[1][0]);
      acc[1][1] = mfma16h(a1, Bcur[kt*2+1], acc[1][1]);
    }

    if (t < 126){
      const int ps = isR ? (125 - t) : (t + 2);   // phi local slot
      unsigned* Wbuf = &AfragU[((t+1) & 1) * 4096];
      #pragma unroll
      for (int mt = 0; mt < 2; ++mt){
        uint4 phiu = *(const uint4*)&phiT[ps*32 + 16*mt + 4*q];
        const unsigned pr[4] = {phiu.x, phiu.y, phiu.z, phiu.w};
        #pragma unroll
        for (int nb = 0; nb < 2; ++nb){
          unsigned u[4], f[4];
          #pragma unroll
          for (int reg = 0; reg < 4; ++reg)
            u[reg] = mul_phi(acc[mt][nb][reg], pr[reg]);
          xpose4(u, f, t3);
          *(uint4*)&Wbuf[((mt*8 + (2*w + nb))*64 + lamf)*4] =
              make_uint4(f[0], f[1], f[2], f[3]);
        }
      }
    } else if (isR){
      // right final: store R^T[col][row], fence, flag
      #pragma unroll
      for (int mt = 0; mt < 2; ++mt)
        #pragma unroll
        for (int nb = 0; nb < 2; ++nb){
          const int col = 16*(2*w + nb) + r;
          float4 v4 = make_float4(acc[mt][nb][0], acc[mt][nb][1],
                                  acc[mt][nb][2], acc[mt][nb][3]);
          *(float4*)&RT[col*32 + 16*mt + 4*q] = v4;
        }
      __threadfence();
      __syncthreads();
      if (tid == 0) atomicExch(flagp, MAGIC);
    } else {
      // left final: wait for R, dot, reduce, linear head
      if (tid < 32) scal[tid] = 0.0f;
      if (tid == 0){
        while (atomicAdd(flagp, 0u) != MAGIC) __builtin_amdgcn_s_sleep(8);
      }
      __syncthreads();
      __threadfence();
      float part[2][4] = {};
      #pragma unroll
      for (int mt = 0; mt < 2; ++mt)
        #pragma unroll
        for (int nb = 0; nb < 2; ++nb){
          const int col = 16*(2*w + nb) + r;
          float4 rv = *(const float4*)&RT[col*32 + 16*mt + 4*q];
          part[mt][0] += acc[mt][nb][0] * rv.x;
          part[mt][1] += acc[mt][nb][1] * rv.y;
          part[mt][2] += acc[mt][nb][2] * rv.z;
          part[mt][3] += acc[mt][nb][3] * rv.w;
        }
      #pragma unroll
      for (int m = 1; m < 16; m <<= 1)
        #pragma unroll
        for (int mt = 0; mt < 2; ++mt)
          #pragma unroll
          for (int reg = 0; reg < 4; ++reg)
            part[mt][reg] += __shfl_xor(part[mt][reg], m);
      if (r == 0){
        #pragma unroll
        for (int mt = 0; mt < 2; ++mt)
          #pragma unroll
          for (int reg = 0; reg < 4; ++reg)
            atomicAdd(&scal[16*mt + 4*q + reg], part[mt][reg]);
      }
      __syncthreads();
      for (int t2 = tid; t2 < 320; t2 += 256){
        int bb = t2 / 10, o = t2 - bb*10;
        out[(size_t)(rowbase + bb)*10 + o] = scal[bb]*wlin[o] + blin[o];
      }
    }
  };

  #pragma unroll 1
  for (int t = 0; t < 126; t += 2){
    body(t,     Breg0, Breg1);
    body(t + 1, Breg1, Breg0);
  }
  body(126, Breg0, Breg1);
}

extern "C" void kernel_launch(void* const* d_in, const int* in_sizes, int n_in,
                              void* d_out, int out_size, void* d_ws, size_t ws_size,
                              hipStream_t stream){
  (void)in_sizes; (void)n_in; (void)out_size; (void)ws_size;
  const float* x     = (const float*)d_in[0];
  const float* first = (const float*)d_in[1];
  const float* mid   = (const float*)d_in[2];
  const float* lastw = (const float*)d_in[3];
  const float* wlin  = (const float*)d_in[4];
  const float* blin  = (const float*)d_in[5];
  float* o            = (float*)d_out;
  unsigned short* wsB = (unsigned short*)d_ws;   // frag slots 0..253 (16.6 MB)
  float* ws_f         = (float*)d_ws;            // + R^T (4 MB) + flags

  hipLaunchKernelGGL(repack_all, dim3(2540), dim3(256), 0, stream, mid, wsB);
  hipLaunchKernelGGL(mps_main,   dim3(512),  dim3(256), 0, stream,
                     x, first, wsB, lastw, wlin, blin, ws_f, o);
}

// Round 9
// 335.196 us; speedup vs baseline: 1.0203x; 1.0203x over previous
//
#include <hip/hip_runtime.h>

// MPS classifier, MI355X gfx950. Round 9: r8 + forced B-prefetch residency.
// r6/r7/r8 all ~270-280us: VGPR_Count=68 proved the compiler SANK the B
// register prefetch past the barrier to its use site (Breg0+Breg1 need 128
// VGPRs) -> per-kt load-use L2 blocking (~300cyc x 8kt = measured step time).
// Fix: asm keep-alives on Bcur before each barrier pin the loads one full
// step ahead of use; barrier's vmcnt(0) drain completes them -> MFMA never
// waits on L2.
// Structure unchanged from r8: 512 WGs x 256 thr (2 WGs/CU), left/right
// split chain, M=32 rows/WG, one barrier/step, dbuf A-frags in LDS,
// DPP-transpose epilogue, packed-f16 phi table.

typedef _Float16 v8h __attribute__((ext_vector_type(8)));
typedef _Float16 h2  __attribute__((ext_vector_type(2)));
typedef float    v4f __attribute__((ext_vector_type(4)));

#define PI_HALF 1.5707963267948966f
#define SITE_U4 4096                       // uint4 per frag slot (64 KB)
#define RT_F32_BASE (254u*65536u/4u)       // float offset of R^T region
#define FLAG_BASE   (RT_F32_BASE + 256u*4096u)
#define MAGIC 0x13572468u

union U4H8 { uint4 u; v8h h; };

__device__ __forceinline__ v4f mfma16h(uint4 a, uint4 b, v4f c){
  U4H8 ua, ub; ua.u = a; ub.u = b;
  return __builtin_amdgcn_mfma_f32_16x16x32_f16(ua.h, ub.h, c, 0, 0, 0);
}
__device__ __forceinline__ unsigned pack2h(float lo, float hi){
  h2 p; p[0] = (_Float16)lo; p[1] = (_Float16)hi;
  return __builtin_bit_cast(unsigned, p);
}
__device__ __forceinline__ unsigned mul_phi(float v, unsigned phiu){
  _Float16 vh = (_Float16)v;
  h2 vv; vv[0] = vh; vv[1] = vh;
  h2 ph = __builtin_bit_cast(h2, phiu);
  h2 r = vv * ph;
  return __builtin_bit_cast(unsigned, r);
}
__device__ __forceinline__ unsigned dpp_xor1(unsigned x){
  return (unsigned)__builtin_amdgcn_mov_dpp((int)x, 0xB1, 0xF, 0xF, true);
}
__device__ __forceinline__ unsigned dpp_xor2(unsigned x){
  return (unsigned)__builtin_amdgcn_mov_dpp((int)x, 0x4E, 0xF, 0xF, true);
}
__device__ __forceinline__ void xpose4(const unsigned u[4], unsigned f[4], int t){
  unsigned q0 = dpp_xor1(u[0]), q1 = dpp_xor1(u[1]);
  unsigned q2 = dpp_xor1(u[2]), q3 = dpp_xor1(u[3]);
  bool b0 = (t & 1);
  unsigned h0 = b0 ? q1 : u[0];
  unsigned h1 = b0 ? u[1] : q0;
  unsigned h2_ = b0 ? q3 : u[2];
  unsigned h3 = b0 ? u[3] : q2;
  unsigned r0 = dpp_xor2(h0), r1 = dpp_xor2(h1);
  unsigned r2 = dpp_xor2(h2_), r3 = dpp_xor2(h3);
  bool b1 = (t & 2);
  f[0] = b1 ? r2 : h0;
  f[1] = b1 ? r3 : h1;
  f[2] = b1 ? h2_ : r0;
  f[3] = b1 ? h3 : r1;
}
// Pin a prefetched uint4 in VGPRs at this program point (defeats load sinking).
__device__ __forceinline__ void keep(uint4 &v){
  asm volatile("" : "+v"(v.x), "+v"(v.y), "+v"(v.z), "+v"(v.w));
}

// ---------------------------------------------------------------------------
// Combined repack (mid read once; each site has exactly one format):
// blocks 0..507: L-format, slots 0..126 (sites 1..127):
//   wsB[slot][kt][ntg][lane] uint4, elem (lane,j) = M[k=32kt+8q+j][n], k=2l+d.
// blocks 508..2539: R-format, slots 127..253 (sites 128..254):
//   B~[k=2r+d][n=l] = midrow(l)[(k&1)*128 + (k>>1)].
// ---------------------------------------------------------------------------
__global__ __launch_bounds__(256) void repack_all(const float* __restrict__ mid,
                                                  unsigned short* __restrict__ wsB){
  const int bid = blockIdx.x;
  if (bid < 508){
    int idx  = bid * 256 + threadIdx.x;        // 127*1024
    int lg   = idx & 15;
    int nt   = (idx >> 4) & 7;
    int kt   = (idx >> 7) & 7;
    int site = idx >> 10;                      // 0..126
    int q    = lg >> 2;
    int n0   = 16*nt + 4*(lg & 3);
    const float* src = mid + (size_t)site*32768 + (size_t)(32*kt + 8*q)*128 + n0;
    float Lv[4][4], Hv[4][4];
    #pragma unroll
    for (int jp = 0; jp < 4; ++jp){
      float4 a = *(const float4*)(src + (size_t)(2*jp)*128);
      float4 b = *(const float4*)(src + (size_t)(2*jp+1)*128);
      Lv[jp][0]=a.x; Lv[jp][1]=a.y; Lv[jp][2]=a.z; Lv[jp][3]=a.w;
      Hv[jp][0]=b.x; Hv[jp][1]=b.y; Hv[jp][2]=b.z; Hv[jp][3]=b.w;
    }
    uint4* dst = (uint4*)wsB + (((size_t)(site*8 + kt)*8 + nt)*64 + 16*q + 4*(lg&3));
    #pragma unroll
    for (int t = 0; t < 4; ++t){
      uint4 o;
      o.x = pack2h(Lv[0][t], Hv[0][t]);
      o.y = pack2h(Lv[1][t], Hv[1][t]);
      o.z = pack2h(Lv[2][t], Hv[2][t]);
      o.w = pack2h(Lv[3][t], Hv[3][t]);
      dst[t] = o;
    }
  } else {
    int idx  = (bid - 508) * 256 + threadIdx.x;  // 127*4096
    int lane = idx & 63;
    int ntg  = (idx >> 6) & 7;
    int kt   = (idx >> 9) & 7;
    int site = 127 + (idx >> 12);                // 127..253
    int q    = lane >> 4;
    int n    = 16*ntg + (lane & 15);
    int rb   = 16*kt + 4*q;
    const float* row = mid + (size_t)site*32768 + (size_t)n*256;
    float4 d0 = *(const float4*)(row + rb);
    float4 d1 = *(const float4*)(row + 128 + rb);
    unsigned p0 = pack2h(d0.x, d1.x);
    unsigned p1 = pack2h(d0.y, d1.y);
    unsigned p2 = pack2h(d0.z, d1.z);
    unsigned p3 = pack2h(d0.w, d1.w);
    ((uint4*)wsB)[((size_t)(site*8 + kt)*8 + ntg)*64 + lane] =
        make_uint4(p0, p1, p2, p3);
  }
}

// ---------------------------------------------------------------------------
// Main. 512 WGs x 256 thr (2 WGs/CU). LDS: phiT[128 sites][32 rows] 16 KB;
// AfragU 2 bufs x 16 KB; scal[32]. ~48.3 KB -> two WGs/CU.
// A-frag: lane L holds A[m=16mt+(L&15)][k=32kt+8(L>>4)+j].
// ---------------------------------------------------------------------------
__global__ __launch_bounds__(256, 2) void mps_main(
    const float* __restrict__ x,               // [8192][256]
    const float* __restrict__ first,           // [2][128]
    const unsigned short* __restrict__ wsB,    // frag slots 0..253
    const float* __restrict__ lastw,           // [128][2]
    const float* __restrict__ wlin,            // [10]
    const float* __restrict__ blin,            // [10]
    float* __restrict__ ws_f,                  // ws as float (R^T + flags)
    float* __restrict__ out)                   // [8192][10]
{
  __shared__ unsigned phiT[128*32];
  __shared__ unsigned AfragU[2*2*8*64*4];      // 2 bufs x 4096 uints
  __shared__ float scal[32];

  const int tid  = threadIdx.x;
  const int g    = blockIdx.x;
  const int pair = g >> 1;
  const int isR  = g & 1;
  const int w    = tid >> 6;                   // wave: cols [32w, 32w+32)
  const int lane = tid & 63;
  const int r    = lane & 15;
  const int q    = lane >> 4;
  const int rowbase = pair * 32;
  const int phbase  = isR ? 128 : 0;

  float* RT = ws_f + RT_F32_BASE + (size_t)pair * 4096;  // [col][row] f32
  unsigned* flagp = (unsigned*)(ws_f + FLAG_BASE) + pair;

  // ---- Phase 1: feature map -> packed f16 (cos,sin), own half only ----
  {
    const int row = tid >> 3;            // 0..31
    const int c   = tid & 7;             // 32-site chunk
    const float4* xp = (const float4*)(x + (size_t)(rowbase + row) * 256 + c*32);
    float xv[32];
    float vmin = 3.0e38f, vmax = -3.0e38f;
    #pragma unroll
    for (int cc = 0; cc < 8; ++cc){
      float4 u = xp[cc];
      xv[cc*4+0]=u.x; xv[cc*4+1]=u.y; xv[cc*4+2]=u.z; xv[cc*4+3]=u.w;
      vmin = fminf(vmin, fminf(fminf(u.x,u.y), fminf(u.z,u.w)));
      vmax = fmaxf(vmax, fmaxf(fmaxf(u.x,u.y), fmaxf(u.z,u.w)));
    }
    #pragma unroll
    for (int m = 1; m < 8; m <<= 1){
      vmin = fminf(vmin, __shfl_xor(vmin, m));
      vmax = fmaxf(vmax, __shfl_xor(vmax, m));
    }
    const float sc = PI_HALF / (vmax - vmin + 1e-6f);
    #pragma unroll
    for (int j = 0; j < 32; ++j){
      int site = c*32 + j;
      int loc  = site - phbase;
      if (loc >= 0 && loc < 128){
        float a = (xv[j] - vmin) * sc;
        phiT[loc*32 + row] = pack2h(__cosf(a), __sinf(a));
      }
    }
  }
  __syncthreads();

  // ---- Phase 2: seed A-frags for step 0 (buf 0) ----
  {
    const int s_init = isR ? 127 : 0;
    const int s_next = isR ? 126 : 1;
    #pragma unroll
    for (int mt = 0; mt < 2; ++mt){
      const int m = 16*mt + r;
      h2 ph0 = __builtin_bit_cast(h2, phiT[s_init*32 + m]);
      const float c0v = (float)ph0[0], s0v = (float)ph0[1];
      const unsigned phn = phiT[s_next*32 + m];
      #pragma unroll
      for (int ktb = 0; ktb < 2; ++ktb){
        const int kt = 2*w + ktb;
        unsigned u[4];
        #pragma unroll
        for (int jp = 0; jp < 4; ++jp){
          const int l = 16*kt + 4*q + jp;
          float f0 = isR ? lastw[2*l]     : first[l];
          float f1 = isR ? lastw[2*l + 1] : first[128 + l];
          float v  = f0*c0v + f1*s0v;
          u[jp] = mul_phi(v, phn);
        }
        *(uint4*)&AfragU[((mt*8 + kt)*64 + lane)*4] =
            make_uint4(u[0], u[1], u[2], u[3]);
      }
    }
  }

  // ---- B prefetch step 0 (slot: left = t, right = 253-t) ----
  uint4 Breg0[16], Breg1[16];
  {
    const int slot = isR ? 253 : 0;
    const uint4* bp = (const uint4*)wsB + (size_t)slot * SITE_U4;
    #pragma unroll
    for (int kt = 0; kt < 8; ++kt)
      #pragma unroll
      for (int nb = 0; nb < 2; ++nb)
        Breg0[kt*2+nb] = bp[(size_t)(kt*8 + 2*w + nb)*64 + lane];
  }

  const int t3   = lane & 3;
  const int lamf = 16*((lane>>2)&3) + 4*(lane>>4) + t3;

  auto body = [&](int t, uint4 (&Bcur)[16], uint4 (&Bnxt)[16]){
    // Pin the B loads issued last step BEFORE the barrier: the barrier's
    // vmcnt(0) drain completes them here, so the MFMA loop never waits on
    // L2, and the compiler cannot sink the loads past the barrier.
    #pragma unroll
    for (int i2 = 0; i2 < 16; ++i2) keep(Bcur[i2]);
    __syncthreads();

    // prefetch B for step t+1 (clamped; unused at t=126)
    {
      const int tn   = (t < 126) ? (t + 1) : 126;
      const int slot = isR ? (253 - tn) : tn;
      const uint4* bp = (const uint4*)wsB + (size_t)slot * SITE_U4;
      #pragma unroll
      for (int kt = 0; kt < 8; ++kt)
        #pragma unroll
        for (int nb = 0; nb < 2; ++nb)
          Bnxt[kt*2+nb] = bp[(size_t)(kt*8 + 2*w + nb)*64 + lane];
    }

    // MFMA: C[0..32)[32w..32w+32)
    v4f acc[2][2] = {};   // [mt][nb]; row=16mt+4q+reg, col=16(2w+nb)+r
    const unsigned* Abuf = &AfragU[(t & 1) * 4096];
    #pragma unroll
    for (int kt = 0; kt < 8; ++kt){
      uint4 a0 = *(const uint4*)&Abuf[((0*8 + kt)*64 + lane)*4];
      uint4 a1 = *(const uint4*)&Abuf[((1*8 + kt)*64 + lane)*4];
      acc[0][0] = mfma16h(a0, Bcur[kt*2+0], acc[0][0]);
      acc[0][1] = mfma16h(a0, Bcur[kt*2+1], acc[0][1]);
      acc[1][0] = mfma16h(a1, Bcur[kt*2+0], acc[1][0]);
      acc[1][1] = mfma16h(a1, Bcur[kt*2+1], acc[1][1]);
    }

    if (t < 126){
      const int ps = isR ? (125 - t) : (t + 2);   // phi local slot
      unsigned* Wbuf = &AfragU[((t+1) & 1) * 4096];
      #pragma unroll
      for (int mt = 0; mt < 2; ++mt){
        uint4 phiu = *(const uint4*)&phiT[ps*32 + 16*mt + 4*q];
        const unsigned pr[4] = {phiu.x, phiu.y, phiu.z, phiu.w};
        #pragma unroll
        for (int nb = 0; nb < 2; ++nb){
          unsigned u[4], f[4];
          #pragma unroll
          for (int reg = 0; reg < 4; ++reg)
            u[reg] = mul_phi(acc[mt][nb][reg], pr[reg]);
          xpose4(u, f, t3);
          *(uint4*)&Wbuf[((mt*8 + (2*w + nb))*64 + lamf)*4] =
              make_uint4(f[0], f[1], f[2], f[3]);
        }
      }
    } else if (isR){
      // right final: store R^T[col][row], fence, flag
      #pragma unroll
      for (int mt = 0; mt < 2; ++mt)
        #pragma unroll
        for (int nb = 0; nb < 2; ++nb){
          const int col = 16*(2*w + nb) + r;
          float4 v4 = make_float4(acc[mt][nb][0], acc[mt][nb][1],
                                  acc[mt][nb][2], acc[mt][nb][3]);
          *(float4*)&RT[col*32 + 16*mt + 4*q] = v4;
        }
      __threadfence();
      __syncthreads();
      if (tid == 0) atomicExch(flagp, MAGIC);
    } else {
      // left final: wait for R, dot, reduce, linear head
      if (tid < 32) scal[tid] = 0.0f;
      if (tid == 0){
        while (atomicAdd(flagp, 0u) != MAGIC) __builtin_amdgcn_s_sleep(8);
      }
      __syncthreads();
      __threadfence();
      float part[2][4] = {};
      #pragma unroll
      for (int mt = 0; mt < 2; ++mt)
        #pragma unroll
        for (int nb = 0; nb < 2; ++nb){
          const int col = 16*(2*w + nb) + r;
          float4 rv = *(const float4*)&RT[col*32 + 16*mt + 4*q];
          part[mt][0] += acc[mt][nb][0] * rv.x;
          part[mt][1] += acc[mt][nb][1] * rv.y;
          part[mt][2] += acc[mt][nb][2] * rv.z;
          part[mt][3] += acc[mt][nb][3] * rv.w;
        }
      #pragma unroll
      for (int m = 1; m < 16; m <<= 1)
        #pragma unroll
        for (int mt = 0; mt < 2; ++mt)
          #pragma unroll
          for (int reg = 0; reg < 4; ++reg)
            part[mt][reg] += __shfl_xor(part[mt][reg], m);
      if (r == 0){
        #pragma unroll
        for (int mt = 0; mt < 2; ++mt)
          #pragma unroll
          for (int reg = 0; reg < 4; ++reg)
            atomicAdd(&scal[16*mt + 4*q + reg], part[mt][reg]);
      }
      __syncthreads();
      for (int t2 = tid; t2 < 320; t2 += 256){
        int bb = t2 / 10, o = t2 - bb*10;
        out[(size_t)(rowbase + bb)*10 + o] = scal[bb]*wlin[o] + blin[o];
      }
    }
  };

  #pragma unroll 1
  for (int t = 0; t < 126; t += 2){
    body(t,     Breg0, Breg1);
    body(t + 1, Breg1, Breg0);
  }
  body(126, Breg0, Breg1);
}

extern "C" void kernel_launch(void* const* d_in, const int* in_sizes, int n_in,
                              void* d_out, int out_size, void* d_ws, size_t ws_size,
                              hipStream_t stream){
  (void)in_sizes; (void)n_in; (void)out_size; (void)ws_size;
  const float* x     = (const float*)d_in[0];
  const float* first = (const float*)d_in[1];
  const float* mid   = (const float*)d_in[2];
  const float* lastw = (const float*)d_in[3];
  const float* wlin  = (const float*)d_in[4];
  const float* blin  = (const float*)d_in[5];
  float* o            = (float*)d_out;
  unsigned short* wsB = (unsigned short*)d_ws;   // frag slots 0..253 (16.6 MB)
  float* ws_f         = (float*)d_ws;            // + R^T (4 MB) + flags

  hipLaunchKernelGGL(repack_all, dim3(2540), dim3(256), 0, stream, mid, wsB);
  hipLaunchKernelGGL(mps_main,   dim3(512),  dim3(256), 0, stream,
                     x, first, wsB, lastw, wlin, blin, ws_f, o);
}